// Round 1
// baseline (129.951 us; speedup 1.0000x reference)
//
#include <hip/hip_runtime.h>
#include <hip/hip_bf16.h>

// GAT layer, N=8192, IN_F=256, OUT_F=64.
// k1: h = input@W (f32), f1 = h@a1, f2 = h@a2; store h transposed as bf16.
// k2: fused masked-softmax(lrelu(f1_i + f2_j)) @ h via 16x16x32 bf16 MFMA.
//     Fixed per-row shift = lrelu(f1_i + max_j f2_j) (monotonicity of lrelu)
//     => no online rescale needed; exp(e-shift) <= 1 always.

using short8 = __attribute__((ext_vector_type(8))) short;
using f32x4  = __attribute__((ext_vector_type(4))) float;

#define NN    8192
#define INF_  256
#define OUTF  64
#define LR_A  0.2f
#define ROWS  16   // output rows per block in k2

__device__ __forceinline__ unsigned short f2bf_rne(float x) {
  unsigned int u = __float_as_uint(x);
  u += 0x7FFFu + ((u >> 16) & 1u);          // round-to-nearest-even
  return (unsigned short)(u >> 16);
}
__device__ __forceinline__ float bf2f(unsigned short s) {
  return __uint_as_float(((unsigned int)s) << 16);
}

// ---------------- kernel 1: h, f1, f2, h_t(bf16) ----------------
__global__ __launch_bounds__(256) void gat_pre(
    const float* __restrict__ input, const float* __restrict__ W,
    const float* __restrict__ a, unsigned short* __restrict__ hbt,
    float* __restrict__ f1, float* __restrict__ f2) {
  __shared__ float Wl[INF_ * OUTF];           // 64 KB
  int tid = threadIdx.x;
  for (int idx = tid; idx < INF_ * OUTF / 4; idx += 256)
    *(float4*)(Wl + idx * 4) = *(const float4*)(W + idx * 4);
  __syncthreads();
  int w = tid >> 6, l = tid & 63;             // 4 waves, lane = output feature
  float a1k = a[l], a2k = a[OUTF + l];
  int i0 = blockIdx.x * 16;                   // 16 rows per block
  for (int r = 0; r < 4; ++r) {
    int i = i0 + w * 4 + r;
    const float4* in4 = (const float4*)(input + (long)i * INF_);
    float h = 0.f;
#pragma unroll 8
    for (int c4 = 0; c4 < INF_ / 4; ++c4) {
      float4 v = in4[c4];                     // wave-uniform broadcast load
      int c = c4 * 4;
      h = fmaf(v.x, Wl[c * OUTF + l], h);
      h = fmaf(v.y, Wl[(c + 1) * OUTF + l], h);
      h = fmaf(v.z, Wl[(c + 2) * OUTF + l], h);
      h = fmaf(v.w, Wl[(c + 3) * OUTF + l], h);
    }
    float t1 = h * a1k, t2 = h * a2k;
#pragma unroll
    for (int off = 32; off; off >>= 1) {
      t1 += __shfl_xor(t1, off);
      t2 += __shfl_xor(t2, off);
    }
    hbt[(long)l * NN + i] = f2bf_rne(h);      // transposed bf16 store h_t[n][j]
    if (l == 0) { f1[i] = t1; f2[i] = t2; }
  }
}

// ---------------- kernel 2: fused attention ----------------
__global__ __launch_bounds__(512, 4) void gat_main(
    const int* __restrict__ adj, const unsigned short* __restrict__ hbt,
    const float* __restrict__ f1, const float* __restrict__ f2,
    float* __restrict__ out) {
  __shared__ float f2s[NN];                   // 32 KB
  __shared__ float accs[8][ROWS][OUTF];       // 32 KB
  __shared__ float ssum[8][ROWS];
  __shared__ float f1s[ROWS], shifts[ROWS], red[8];
  int tid = threadIdx.x;
  int w = tid >> 6, l = tid & 63;
  int i0 = blockIdx.x * ROWS;

  // stage f2 in LDS + global max of f2
  float fm = -1e30f;
  for (int jj = tid; jj < NN; jj += 512) {
    float v = f2[jj];
    f2s[jj] = v;
    fm = fmaxf(fm, v);
  }
#pragma unroll
  for (int off = 32; off; off >>= 1) fm = fmaxf(fm, __shfl_xor(fm, off));
  if (l == 0) red[w] = fm;
  __syncthreads();
  if (tid == 0) {
    float m = red[0];
#pragma unroll
    for (int x = 1; x < 8; ++x) m = fmaxf(m, red[x]);
    red[0] = m;
  }
  __syncthreads();
  float Fmax = red[0];
  if (tid < ROWS) {
    float v = f1[i0 + tid];
    f1s[tid] = v;
    float s = v + Fmax;
    shifts[tid] = fmaxf(s, LR_A * s);         // lrelu(f1+Fmax) >= row max
  }
  __syncthreads();

  int q = l & 15, g = l >> 4;                 // A-frag: row=q, k-group=g
  float f1r = f1s[q], sh = shifts[q];
  const int* adjrow = adj + (long)(i0 + q) * NN;
  f32x4 acc0 = {0.f, 0.f, 0.f, 0.f}, acc1 = acc0, acc2 = acc0, acc3 = acc0;
  float srow = 0.f;

  for (int chunk = w; chunk < NN / 32; chunk += 8) {  // wave handles 32 K-steps
    int jb = chunk * 32 + g * 8;
    int4   av0 = *(const int4*)(adjrow + jb);
    int4   av1 = *(const int4*)(adjrow + jb + 4);
    float4 fv0 = *(const float4*)(f2s + jb);
    float4 fv1 = *(const float4*)(f2s + jb + 4);
    float f2a[8] = {fv0.x, fv0.y, fv0.z, fv0.w, fv1.x, fv1.y, fv1.z, fv1.w};
    int   aa[8]  = {av0.x, av0.y, av0.z, av0.w, av1.x, av1.y, av1.z, av1.w};
    short8 afrag;
#pragma unroll
    for (int e = 0; e < 8; ++e) {
      float x = f1r + f2a[e];
      x = fmaxf(x, LR_A * x);                 // leaky relu
      float pe = (aa[e] > 0) ? __expf(x - sh) : 0.f;
      unsigned short us = f2bf_rne(pe);
      afrag[e] = (short)us;
      srow += bf2f(us);                       // denom consistent with bf16 numer
    }
    const unsigned short* hB = hbt + jb;      // h_t[n][j]: short8 = 8 j's
    short8 b0 = *(const short8*)(hB + (long)(q)      * NN);
    short8 b1 = *(const short8*)(hB + (long)(q + 16) * NN);
    short8 b2 = *(const short8*)(hB + (long)(q + 32) * NN);
    short8 b3 = *(const short8*)(hB + (long)(q + 48) * NN);
    acc0 = __builtin_amdgcn_mfma_f32_16x16x32_bf16(afrag, b0, acc0, 0, 0, 0);
    acc1 = __builtin_amdgcn_mfma_f32_16x16x32_bf16(afrag, b1, acc1, 0, 0, 0);
    acc2 = __builtin_amdgcn_mfma_f32_16x16x32_bf16(afrag, b2, acc2, 0, 0, 0);
    acc3 = __builtin_amdgcn_mfma_f32_16x16x32_bf16(afrag, b3, acc3, 0, 0, 0);
  }

  // full row-sum for row q (combine the 4 k-groups)
  srow += __shfl_xor(srow, 16);
  srow += __shfl_xor(srow, 32);
  if (l < ROWS) ssum[w][l] = srow;

  // D layout: col = l&15 (+nb*16), row = g*4 + reg   [m89-verified]
#pragma unroll
  for (int r = 0; r < 4; ++r) {
    accs[w][g * 4 + r][0 * 16 + q] = acc0[r];
    accs[w][g * 4 + r][1 * 16 + q] = acc1[r];
    accs[w][g * 4 + r][2 * 16 + q] = acc2[r];
    accs[w][g * 4 + r][3 * 16 + q] = acc3[r];
  }
  __syncthreads();

  // combine 8 waves, normalize, elu, write
  for (int idx = tid; idx < ROWS * OUTF; idx += 512) {
    int m = idx >> 6, n = idx & 63;
    float num = 0.f, den = 0.f;
#pragma unroll
    for (int ww = 0; ww < 8; ++ww) {
      num += accs[ww][m][n];
      den += ssum[ww][m];
    }
    float v = num / den;
    out[(long)(i0 + m) * OUTF + n] = v > 0.f ? v : expm1f(v);
  }
}

extern "C" void kernel_launch(void* const* d_in, const int* in_sizes, int n_in,
                              void* d_out, int out_size, void* d_ws, size_t ws_size,
                              hipStream_t stream) {
  const float* input = (const float*)d_in[0];
  const int*   adj   = (const int*)d_in[1];
  const float* W     = (const float*)d_in[2];
  const float* a     = (const float*)d_in[3];
  float* out = (float*)d_out;
  char* ws = (char*)d_ws;
  unsigned short* hbt = (unsigned short*)ws;           // 1 MB  h_t bf16 [64][8192]
  float* f1 = (float*)(ws + (1 << 20));                // 32 KB
  float* f2 = (float*)(ws + (1 << 20) + (32 << 10));   // 32 KB
  (void)in_sizes; (void)n_in; (void)out_size; (void)ws_size;

  gat_pre<<<512, 256, 0, stream>>>(input, W, a, hbt, f1, f2);
  gat_main<<<512, 512, 0, stream>>>(adj, hbt, f1, f2, out);
}

// Round 2
// 101.485 us; speedup vs baseline: 1.2805x; 1.2805x over previous
//
#include <hip/hip_runtime.h>
#include <hip/hip_bf16.h>

// GAT layer, N=8192, IN_F=256, OUT_F=64.
// k1: h = input@W (f32, LDS-transposed W), f1 = h@a1, f2 = h@a2;
//     h stored as bf16 in MFMA-fragment-linear ("packed") order.
// k2: fused masked-softmax(lrelu(f1_i + f2_j)) @ h via 16x16x32 bf16 MFMA.
//     adj staged to LDS with coalesced global_load_lds (1KB/wave-inst),
//     padded rows (1040B) for conflict-free ds_read_b128 fragment reads.
//     Fixed per-row shift = lrelu(f1_i + max_j f2_j) => exp arg <= 0 always.

using short8 = __attribute__((ext_vector_type(8))) short;
using f32x4  = __attribute__((ext_vector_type(4))) float;

#define NN     8192
#define INF_   256
#define OUTF   64
#define LR_A   0.2f
#define ROWS   16            // adj rows per block in k2
#define TILE_C 256           // staged columns per tile
#define NTILES (NN / TILE_C) // 32
#define ROWB   1040          // padded LDS row bytes (1024 data + 16 pad)

__device__ __forceinline__ unsigned short f2bf_rne(float x) {
  unsigned int u = __float_as_uint(x);
  u += 0x7FFFu + ((u >> 16) & 1u);
  return (unsigned short)(u >> 16);
}

// ---------------- kernel 1: h (packed bf16), f1, f2 ----------------
__global__ __launch_bounds__(256) void gat_pre(
    const float* __restrict__ input, const float* __restrict__ W,
    const float* __restrict__ a, unsigned short* __restrict__ hp,
    float* __restrict__ f1, float* __restrict__ f2) {
  __shared__ float WT[OUTF][260];               // transposed W, padded
  int tid = threadIdx.x;
  for (int idx = tid; idx < INF_ * OUTF; idx += 256) {
    int c = idx >> 6, f = idx & 63;
    WT[f][c] = W[idx];                          // W[c][f] -> WT[f][c]
  }
  __syncthreads();
  int w = tid >> 6, l = tid & 63;               // lane = output feature
  int i0 = blockIdx.x * 16 + w * 4;             // 4 rows per thread
  const float4* r0 = (const float4*)(input + (long)(i0 + 0) * INF_);
  const float4* r1 = (const float4*)(input + (long)(i0 + 1) * INF_);
  const float4* r2 = (const float4*)(input + (long)(i0 + 2) * INF_);
  const float4* r3 = (const float4*)(input + (long)(i0 + 3) * INF_);
  float h0 = 0.f, h1 = 0.f, h2 = 0.f, h3 = 0.f;
#pragma unroll 4
  for (int c4 = 0; c4 < INF_ / 4; ++c4) {
    float4 wv = *(const float4*)&WT[l][c4 * 4]; // b128, conflict-free (stride 1040B)
    float4 v0 = r0[c4], v1 = r1[c4], v2 = r2[c4], v3 = r3[c4];
    h0 = fmaf(v0.x, wv.x, h0); h0 = fmaf(v0.y, wv.y, h0);
    h0 = fmaf(v0.z, wv.z, h0); h0 = fmaf(v0.w, wv.w, h0);
    h1 = fmaf(v1.x, wv.x, h1); h1 = fmaf(v1.y, wv.y, h1);
    h1 = fmaf(v1.z, wv.z, h1); h1 = fmaf(v1.w, wv.w, h1);
    h2 = fmaf(v2.x, wv.x, h2); h2 = fmaf(v2.y, wv.y, h2);
    h2 = fmaf(v2.z, wv.z, h2); h2 = fmaf(v2.w, wv.w, h2);
    h3 = fmaf(v3.x, wv.x, h3); h3 = fmaf(v3.y, wv.y, h3);
    h3 = fmaf(v3.z, wv.z, h3); h3 = fmaf(v3.w, wv.w, h3);
  }
  float a1k = a[l], a2k = a[OUTF + l];
  float hh[4] = {h0, h1, h2, h3};
#pragma unroll
  for (int r = 0; r < 4; ++r) {
    int i = i0 + r;
    float t1 = hh[r] * a1k, t2 = hh[r] * a2k;
#pragma unroll
    for (int off = 32; off; off >>= 1) {
      t1 += __shfl_xor(t1, off);
      t2 += __shfl_xor(t2, off);
    }
    // packed (MFMA-fragment-linear) store:
    // granule = ((i>>5)*4 + nb)*64 + g*16 + q ; elem = i&7
    int gran = (((i >> 5) * 4) + (l >> 4)) * 64 + ((i >> 3) & 3) * 16 + (l & 15);
    hp[(long)gran * 8 + (i & 7)] = f2bf_rne(hh[r]);
    if (l == 0) { f1[i] = t1; f2[i] = t2; }
  }
}

// ---------------- kernel 2: fused attention ----------------
__global__ __launch_bounds__(512, 4) void gat_main(
    const int* __restrict__ adj, const unsigned short* __restrict__ hp,
    const float* __restrict__ f1, const float* __restrict__ f2,
    float* __restrict__ out) {
  // staging buffers (2 x 16 rows x 1040B) union'd with epilogue accs[8][16][64]
  __shared__ __align__(16) char um[2 * ROWS * ROWB];   // 33280 B
  __shared__ float ssum[8][ROWS];
  __shared__ float f1s[ROWS], shifts[ROWS], red[8];
  int tid = threadIdx.x;
  int w = tid >> 6, l = tid & 63;
  int i0 = blockIdx.x * ROWS;

  // global max of f2 (for the fixed per-row shift)
  float fm = -1e30f;
  for (int jj = tid; jj < NN; jj += 512) fm = fmaxf(fm, f2[jj]);
#pragma unroll
  for (int off = 32; off; off >>= 1) fm = fmaxf(fm, __shfl_xor(fm, off));
  if (l == 0) red[w] = fm;
  __syncthreads();
  if (tid == 0) {
    float m = red[0];
#pragma unroll
    for (int x = 1; x < 8; ++x) m = fmaxf(m, red[x]);
    red[0] = m;
  }
  __syncthreads();
  float Fmax = red[0];
  if (tid < ROWS) {
    float v = f1[i0 + tid];
    f1s[tid] = v;
    float s = v + Fmax;
    shifts[tid] = fmaxf(s, LR_A * s);           // lrelu(f1+Fmax) >= row max
  }
  __syncthreads();

  int q = l & 15, g = l >> 4;                   // A-frag: row=q, k-group=g
  float f1r = f1s[q], sh = shifts[q];
  float u1 = f1r - sh;                          // arg = max(u1 + f2j, u2 + 0.2*f2j)
  float u2 = LR_A * f1r - sh;
  f32x4 acc0 = {0.f, 0.f, 0.f, 0.f}, acc1 = acc0, acc2 = acc0, acc3 = acc0;
  float srow = 0.f;

  // stage tile t into buffer b: each wave loads rows 2w, 2w+1 (1KB contiguous each)
  auto stage = [&](int t, int b) {
    const int* src0 = adj + (long)(i0 + 2 * w) * NN + t * TILE_C + l * 4;
    const int* src1 = src0 + NN;
    char* d0 = um + b * (ROWS * ROWB) + (2 * w) * ROWB;
    char* d1 = d0 + ROWB;
    __builtin_amdgcn_global_load_lds(
        (const __attribute__((address_space(1))) void*)src0,
        (__attribute__((address_space(3))) void*)d0, 16, 0, 0);
    __builtin_amdgcn_global_load_lds(
        (const __attribute__((address_space(1))) void*)src1,
        (__attribute__((address_space(3))) void*)d1, 16, 0, 0);
  };

  stage(0, 0);
  __syncthreads();                              // vmcnt(0) drain: tile 0 ready

  for (int t = 0; t < NTILES; ++t) {
    int b = t & 1;
    if (t + 1 < NTILES) stage(t + 1, b ^ 1);    // overlaps compute(t)

    const char* base = um + b * (ROWS * ROWB) + q * ROWB + w * 128 + g * 32;
    int4 A0 = *(const int4*)(base);
    int4 A1 = *(const int4*)(base + 16);
    int jb = t * TILE_C + w * 32 + g * 8;
    float4 F0 = *(const float4*)(f2 + jb);
    float4 F1 = *(const float4*)(f2 + jb + 4);
    float fa[8] = {F0.x, F0.y, F0.z, F0.w, F1.x, F1.y, F1.z, F1.w};
    int   aa[8] = {A0.x, A0.y, A0.z, A0.w, A1.x, A1.y, A1.z, A1.w};

    union { short8 v; unsigned short u[8]; } pa;
    float ps = 0.f;
#pragma unroll
    for (int e = 0; e < 8; ++e) {
      float arg = fmaxf(u1 + fa[e], fmaf(LR_A, fa[e], u2));  // lrelu(f1+f2)-sh <= 0
      float pe = (aa[e] > 0) ? __expf(arg) : 0.f;
      ps += pe;
      pa.u[e] = f2bf_rne(pe);
    }
    srow += ps;

    long gb = ((long)(t * 8 + w) * 4) * 64 * 8;  // packed hbt: contiguous per inst
    short8 b0 = *(const short8*)(hp + gb + (0 * 64 + l) * 8);
    short8 b1 = *(const short8*)(hp + gb + (1 * 64 + l) * 8);
    short8 b2 = *(const short8*)(hp + gb + (2 * 64 + l) * 8);
    short8 b3 = *(const short8*)(hp + gb + (3 * 64 + l) * 8);
    acc0 = __builtin_amdgcn_mfma_f32_16x16x32_bf16(pa.v, b0, acc0, 0, 0, 0);
    acc1 = __builtin_amdgcn_mfma_f32_16x16x32_bf16(pa.v, b1, acc1, 0, 0, 0);
    acc2 = __builtin_amdgcn_mfma_f32_16x16x32_bf16(pa.v, b2, acc2, 0, 0, 0);
    acc3 = __builtin_amdgcn_mfma_f32_16x16x32_bf16(pa.v, b3, acc3, 0, 0, 0);

    __syncthreads();                            // buf b consumed; safe to overwrite next iter
  }

  // combine the 4 k-groups' row sums (lanes q, q+16, q+32, q+48)
  srow += __shfl_xor(srow, 16);
  srow += __shfl_xor(srow, 32);
  if (l < ROWS) ssum[w][l] = srow;

  // D layout: col = l&15 (+nb*16), row = g*4 + reg   [m89-verified]
  float* accs = (float*)um;                     // [8][16][64], staging dead
#pragma unroll
  for (int r = 0; r < 4; ++r) {
    accs[(w * ROWS + g * 4 + r) * OUTF + 0 * 16 + q] = acc0[r];
    accs[(w * ROWS + g * 4 + r) * OUTF + 1 * 16 + q] = acc1[r];
    accs[(w * ROWS + g * 4 + r) * OUTF + 2 * 16 + q] = acc2[r];
    accs[(w * ROWS + g * 4 + r) * OUTF + 3 * 16 + q] = acc3[r];
  }
  __syncthreads();

  // combine 8 waves, normalize, elu, write
  for (int idx = tid; idx < ROWS * OUTF; idx += 512) {
    int m = idx >> 6, n = idx & 63;
    float num = 0.f, den = 0.f;
#pragma unroll
    for (int ww = 0; ww < 8; ++ww) {
      num += accs[(ww * ROWS + m) * OUTF + n];
      den += ssum[ww][m];
    }
    float v = num / den;
    out[(long)(i0 + m) * OUTF + n] = v > 0.f ? v : expm1f(v);
  }
}

extern "C" void kernel_launch(void* const* d_in, const int* in_sizes, int n_in,
                              void* d_out, int out_size, void* d_ws, size_t ws_size,
                              hipStream_t stream) {
  const float* input = (const float*)d_in[0];
  const int*   adj   = (const int*)d_in[1];
  const float* W     = (const float*)d_in[2];
  const float* a     = (const float*)d_in[3];
  float* out = (float*)d_out;
  char* ws = (char*)d_ws;
  unsigned short* hp = (unsigned short*)ws;            // 1 MB packed bf16 h
  float* f1 = (float*)(ws + (1 << 20));                // 32 KB
  float* f2 = (float*)(ws + (1 << 20) + (32 << 10));   // 32 KB
  (void)in_sizes; (void)n_in; (void)out_size; (void)ws_size;

  gat_pre<<<512, 256, 0, stream>>>(input, W, a, hp, f1, f2);
  gat_main<<<512, 512, 0, stream>>>(adj, hp, f1, f2, out);
}

// Round 3
// 100.204 us; speedup vs baseline: 1.2969x; 1.0128x over previous
//
#include <hip/hip_runtime.h>
#include <hip/hip_bf16.h>

// GAT layer, N=8192, IN_F=256, OUT_F=64.
// k1 gat_pre : h = input@W; f1 = (h@a1)*log2e, f2 = (h@a2)*log2e;
//              h stored bf16 in MFMA-fragment-linear ("packed") order.
// k2 gat_main: grid (512 row-groups x 4 col-quarters), 256 thr (4 waves).
//              Per block: 16 rows x 2048 cols, 8 tiles of 256 cols staged to
//              LDS via coalesced global_load_lds (1KB/inst), double-buffered.
//              p = exp2(lrelu(f1'+f2') - shift'), shift' = lrelu(f1'+Fmax')
//              (monotone lrelu => exp arg <= 0; identical shift across the 4
//              col-blocks so partials combine exactly). Partial num/den -> ws.
// k3 gat_fin : combine 4 partials, normalize, ELU, write out.

using short8 = __attribute__((ext_vector_type(8))) short;
using f32x4  = __attribute__((ext_vector_type(4))) float;

#define NN     8192
#define INF_   256
#define OUTF   64
#define LR_A   0.2f
#define LOG2E  1.4426950408889634f
#define ROWS   16            // adj rows per block in k2
#define TILE_C 256           // staged columns per tile
#define CQW    2048          // columns per quarter
#define NTILES (CQW / TILE_C)   // 8
#define ROWB   1040          // padded LDS row bytes (1024 data + 16 pad)

__device__ __forceinline__ unsigned short f2bf_rne(float x) {
  unsigned int u = __float_as_uint(x);
  u += 0x7FFFu + ((u >> 16) & 1u);
  return (unsigned short)(u >> 16);
}

// ---------------- kernel 1: h (packed bf16), f1', f2' ----------------
__global__ __launch_bounds__(256) void gat_pre(
    const float* __restrict__ input, const float* __restrict__ W,
    const float* __restrict__ a, unsigned short* __restrict__ hp,
    float* __restrict__ f1, float* __restrict__ f2) {
  __shared__ float WT[OUTF][260];               // transposed W, padded
  int tid = threadIdx.x;
  for (int idx = tid; idx < INF_ * OUTF; idx += 256) {
    int c = idx >> 6, f = idx & 63;
    WT[f][c] = W[idx];                          // W[c][f] -> WT[f][c]
  }
  __syncthreads();
  int w = tid >> 6, l = tid & 63;               // lane = output feature
  int i0 = blockIdx.x * 16 + w * 4;             // 4 rows per thread
  const float4* r0 = (const float4*)(input + (long)(i0 + 0) * INF_);
  const float4* r1 = (const float4*)(input + (long)(i0 + 1) * INF_);
  const float4* r2 = (const float4*)(input + (long)(i0 + 2) * INF_);
  const float4* r3 = (const float4*)(input + (long)(i0 + 3) * INF_);
  float h0 = 0.f, h1 = 0.f, h2 = 0.f, h3 = 0.f;
#pragma unroll 4
  for (int c4 = 0; c4 < INF_ / 4; ++c4) {
    float4 wv = *(const float4*)&WT[l][c4 * 4]; // b128, conflict-free
    float4 v0 = r0[c4], v1 = r1[c4], v2 = r2[c4], v3 = r3[c4];
    h0 = fmaf(v0.x, wv.x, h0); h0 = fmaf(v0.y, wv.y, h0);
    h0 = fmaf(v0.z, wv.z, h0); h0 = fmaf(v0.w, wv.w, h0);
    h1 = fmaf(v1.x, wv.x, h1); h1 = fmaf(v1.y, wv.y, h1);
    h1 = fmaf(v1.z, wv.z, h1); h1 = fmaf(v1.w, wv.w, h1);
    h2 = fmaf(v2.x, wv.x, h2); h2 = fmaf(v2.y, wv.y, h2);
    h2 = fmaf(v2.z, wv.z, h2); h2 = fmaf(v2.w, wv.w, h2);
    h3 = fmaf(v3.x, wv.x, h3); h3 = fmaf(v3.y, wv.y, h3);
    h3 = fmaf(v3.z, wv.z, h3); h3 = fmaf(v3.w, wv.w, h3);
  }
  float a1k = a[l], a2k = a[OUTF + l];
  float hh[4] = {h0, h1, h2, h3};
#pragma unroll
  for (int r = 0; r < 4; ++r) {
    int i = i0 + r;
    float t1 = hh[r] * a1k, t2 = hh[r] * a2k;
#pragma unroll
    for (int off = 32; off; off >>= 1) {
      t1 += __shfl_xor(t1, off);
      t2 += __shfl_xor(t2, off);
    }
    // packed store: granule = (K32*4 + nb)*64 + g_i*16 + (feat&15), elem = i&7
    int gran = (((i >> 5) * 4) + (l >> 4)) * 64 + ((i >> 3) & 3) * 16 + (l & 15);
    hp[(long)gran * 8 + (i & 7)] = f2bf_rne(hh[r]);
    if (l == 0) { f1[i] = t1 * LOG2E; f2[i] = t2 * LOG2E; }
  }
}

// ---------------- kernel 2: fused attention (partial over col quarter) ------
__global__ __launch_bounds__(256, 4) void gat_main(
    const int* __restrict__ adj, const unsigned short* __restrict__ hp,
    const float* __restrict__ f1, const float* __restrict__ f2,
    float* __restrict__ numP, float* __restrict__ denP) {
  __shared__ __align__(16) char um[2 * ROWS * ROWB];   // 33280 B (dbuf staging)
  __shared__ float ssum[4][ROWS];
  __shared__ float f1s[ROWS], shifts[ROWS], red[4];
  int tid = threadIdx.x;
  int w = tid >> 6, l = tid & 63;
  int i0 = blockIdx.x * ROWS;
  int cq = blockIdx.y;                          // column quarter 0..3

  // global max of f2' (for the fixed per-row shift — must be column-global)
  float fm = -1e30f;
  for (int jj = tid * 4; jj < NN; jj += 256 * 4) {
    float4 v = *(const float4*)(f2 + jj);
    fm = fmaxf(fm, fmaxf(fmaxf(v.x, v.y), fmaxf(v.z, v.w)));
  }
#pragma unroll
  for (int off = 32; off; off >>= 1) fm = fmaxf(fm, __shfl_xor(fm, off));
  if (l == 0) red[w] = fm;
  __syncthreads();
  if (tid == 0) {
    float m = fmaxf(fmaxf(red[0], red[1]), fmaxf(red[2], red[3]));
    red[0] = m;
  }
  __syncthreads();
  float Fmax = red[0];
  if (tid < ROWS) {
    float v = f1[i0 + tid];
    f1s[tid] = v;
    float s = v + Fmax;
    shifts[tid] = fmaxf(s, LR_A * s);           // lrelu(f1'+Fmax') >= row max
  }
  __syncthreads();

  int q = l & 15, g = l >> 4;                   // A-frag: row=q, k-group=g
  float f1r = f1s[q], sh = shifts[q];
  float u1 = f1r - sh;                          // arg = max(u1+f2j, u2+0.2*f2j)
  float u2 = LR_A * f1r - sh;
  f32x4 acc0 = {0.f, 0.f, 0.f, 0.f}, acc1 = acc0, acc2 = acc0, acc3 = acc0;
  float srow = 0.f;

  const int* adjb = adj + (long)cq * CQW;       // this quarter's columns

  // stage tile t into buffer b: wave w loads rows 4w..4w+3 (1KB contiguous)
  auto stage = [&](int t, int b) {
#pragma unroll
    for (int k = 0; k < 4; ++k) {
      int r = w * 4 + k;
      const int* src = adjb + (long)(i0 + r) * NN + t * TILE_C + l * 4;
      char* d = um + b * (ROWS * ROWB) + r * ROWB;
      __builtin_amdgcn_global_load_lds(
          (const __attribute__((address_space(1))) void*)src,
          (__attribute__((address_space(3))) void*)d, 16, 0, 0);
    }
  };

  stage(0, 0);
  __syncthreads();                              // vmcnt(0) drain: tile 0 ready

  for (int t = 0; t < NTILES; ++t) {
    int b = t & 1;
    if (t + 1 < NTILES) stage(t + 1, b ^ 1);    // overlaps compute(t)

    const char* base = um + b * (ROWS * ROWB) + q * ROWB;
#pragma unroll
    for (int s = 0; s < 2; ++s) {               // 2 K-steps of 32 per wave
      int koff = w * 256 + s * 128 + g * 32;
      int4 A0 = *(const int4*)(base + koff);
      int4 A1 = *(const int4*)(base + koff + 16);
      int jb = cq * CQW + t * TILE_C + w * 64 + s * 32 + g * 8;
      float4 F0 = *(const float4*)(f2 + jb);
      float4 F1 = *(const float4*)(f2 + jb + 4);
      float fa[8] = {F0.x, F0.y, F0.z, F0.w, F1.x, F1.y, F1.z, F1.w};
      int   aa[8] = {A0.x, A0.y, A0.z, A0.w, A1.x, A1.y, A1.z, A1.w};

      union { short8 v; unsigned short u[8]; } pa;
      float ps = 0.f;
#pragma unroll
      for (int e = 0; e < 8; ++e) {
        float arg = fmaxf(u1 + fa[e], fmaf(LR_A, fa[e], u2));
        float pe = (aa[e] > 0) ? exp2f(arg) : 0.f;
        ps += pe;
        pa.u[e] = f2bf_rne(pe);
      }
      srow += ps;

      int K32 = cq * 64 + t * 8 + w * 2 + s;
      const unsigned short* hb = hp + (long)K32 * 4 * 64 * 8 + l * 8;
      short8 b0 = *(const short8*)(hb + 0 * 64 * 8);
      short8 b1 = *(const short8*)(hb + 1 * 64 * 8);
      short8 b2 = *(const short8*)(hb + 2 * 64 * 8);
      short8 b3 = *(const short8*)(hb + 3 * 64 * 8);
      acc0 = __builtin_amdgcn_mfma_f32_16x16x32_bf16(pa.v, b0, acc0, 0, 0, 0);
      acc1 = __builtin_amdgcn_mfma_f32_16x16x32_bf16(pa.v, b1, acc1, 0, 0, 0);
      acc2 = __builtin_amdgcn_mfma_f32_16x16x32_bf16(pa.v, b2, acc2, 0, 0, 0);
      acc3 = __builtin_amdgcn_mfma_f32_16x16x32_bf16(pa.v, b3, acc3, 0, 0, 0);
    }
    __syncthreads();                            // buf b consumed; next overwrite ok
  }

  // row sums: combine the 4 k-groups (lanes q, q+16, q+32, q+48)
  srow += __shfl_xor(srow, 16);
  srow += __shfl_xor(srow, 32);
  if (l < ROWS) ssum[w][l] = srow;

  // D layout: col = l&15 (+nb*16), row = g*4 + reg   [m89-verified]
  float* accs = (float*)um;                     // [4][16][64], staging dead
#pragma unroll
  for (int r = 0; r < 4; ++r) {
    accs[(w * ROWS + g * 4 + r) * OUTF + 0 * 16 + q] = acc0[r];
    accs[(w * ROWS + g * 4 + r) * OUTF + 1 * 16 + q] = acc1[r];
    accs[(w * ROWS + g * 4 + r) * OUTF + 2 * 16 + q] = acc2[r];
    accs[(w * ROWS + g * 4 + r) * OUTF + 3 * 16 + q] = acc3[r];
  }
  __syncthreads();

  // combine 4 waves, write partial num/den for this column quarter
  for (int idx = tid; idx < ROWS * OUTF; idx += 256) {
    int m = idx >> 6, n = idx & 63;
    float num = 0.f, den = 0.f;
#pragma unroll
    for (int ww = 0; ww < 4; ++ww) {
      num += accs[(ww * ROWS + m) * OUTF + n];
      den += ssum[ww][m];
    }
    numP[((long)cq * NN + i0 + m) * OUTF + n] = num;
    if (n == 0) denP[(long)cq * NN + i0 + m] = den;
  }
}

// ---------------- kernel 3: combine quarters, normalize, ELU ----------------
__global__ __launch_bounds__(256) void gat_fin(
    const float* __restrict__ numP, const float* __restrict__ denP,
    float* __restrict__ out) {
  int gid = blockIdx.x * 256 + threadIdx.x;     // [0, 8192*64)
  int row = gid >> 6, n = gid & 63;
  float num = 0.f, den = 0.f;
#pragma unroll
  for (int c = 0; c < 4; ++c) {
    num += numP[((long)c * NN + row) * OUTF + n];
    den += denP[(long)c * NN + row];
  }
  float v = num / den;
  out[gid] = v > 0.f ? v : expm1f(v);
}

extern "C" void kernel_launch(void* const* d_in, const int* in_sizes, int n_in,
                              void* d_out, int out_size, void* d_ws, size_t ws_size,
                              hipStream_t stream) {
  const float* input = (const float*)d_in[0];
  const int*   adj   = (const int*)d_in[1];
  const float* W     = (const float*)d_in[2];
  const float* a     = (const float*)d_in[3];
  float* out = (float*)d_out;
  char* ws = (char*)d_ws;
  unsigned short* hp = (unsigned short*)ws;             // 1 MB packed bf16 h
  float* f1   = (float*)(ws + (1 << 20));               // 32 KB (log2e-scaled)
  float* f2   = (float*)(ws + (1 << 20) + (32 << 10));  // 32 KB (log2e-scaled)
  float* numP = (float*)(ws + (1 << 20) + (64 << 10));  // 8 MB [4][8192][64]
  float* denP = (float*)(ws + (1 << 20) + (64 << 10) + (8 << 20)); // 128 KB
  (void)in_sizes; (void)n_in; (void)out_size; (void)ws_size;

  gat_pre<<<512, 256, 0, stream>>>(input, W, a, hp, f1, f2);
  gat_main<<<dim3(512, 4), 256, 0, stream>>>(adj, hp, f1, f2, numP, denP);
  gat_fin<<<NN * OUTF / 256, 256, 0, stream>>>(numP, denP, out);
}